// Round 5
// baseline (467.148 us; speedup 1.0000x reference)
//
#include <hip/hip_runtime.h>
#include <hip/hip_bf16.h>

#define NEG_SLOPE 0.2f

// ============ Layer 1 GEMM: (N,128)x(128,256), 16 rows/block ============
// Thread t = output col t. Row data x is block-uniform -> SGPR s_load;
// inner loop is pure v_fma_f32(v, s, v) + coalesced W1 loads. No LDS.
__global__ __launch_bounds__(256) void k_gemm1_att(
    const float* __restrict__ x, const float* __restrict__ W1,
    const float* __restrict__ as1, const float* __restrict__ ad1,
    __hip_bfloat16* __restrict__ h1b, float* __restrict__ a_s1, float* __restrict__ a_d1)
{
    const int n0 = blockIdx.x * 16, t = threadIdx.x;
    const float* __restrict__ xr = x + (size_t)n0 * 128;
    float acc[16];
#pragma unroll
    for (int r = 0; r < 16; ++r) acc[r] = 0.f;
#pragma unroll 2
    for (int k = 0; k < 128; k += 4) {
        float w0 = W1[(k + 0) * 256 + t];
        float w1 = W1[(k + 1) * 256 + t];
        float w2 = W1[(k + 2) * 256 + t];
        float w3 = W1[(k + 3) * 256 + t];
#pragma unroll
        for (int r = 0; r < 16; ++r) {
            acc[r] += xr[r * 128 + k] * w0 + xr[r * 128 + k + 1] * w1
                    + xr[r * 128 + k + 2] * w2 + xr[r * 128 + k + 3] * w3;
        }
    }
    float vas = as1[t], vad = ad1[t];
    const int h = t >> 6;
#pragma unroll
    for (int r = 0; r < 16; ++r) {
        h1b[(size_t)(n0 + r) * 256 + t] = __float2bfloat16(acc[r]);
        float s = acc[r] * vas, d = acc[r] * vad;
#pragma unroll
        for (int o = 32; o > 0; o >>= 1) { s += __shfl_down(s, o); d += __shfl_down(d, o); }
        if ((t & 63) == 0) { a_s1[(n0 + r) * 4 + h] = s; a_d1[(n0 + r) * 4 + h] = d; }
    }
}

// ============ CSR build ============
__global__ void k_hist(const int* __restrict__ ei, int E, int M, int* __restrict__ deg)
{
    int i = blockIdx.x * blockDim.x + threadIdx.x;
    if (i >= M) return;
    int dst = (i < E) ? ei[E + i] : (i - E);
    atomicAdd(&deg[dst], 1);
}

__global__ __launch_bounds__(256) void k_scan1(const int* __restrict__ deg, int N,
    int* __restrict__ excl, int* __restrict__ bsum)
{
    __shared__ int s[256];
    int t = threadIdx.x, i = blockIdx.x * 256 + t;
    int v = (i < N) ? deg[i] : 0;
    s[t] = v; __syncthreads();
#pragma unroll
    for (int o = 1; o < 256; o <<= 1) {
        int x = (t >= o) ? s[t - o] : 0;
        __syncthreads();
        s[t] += x;
        __syncthreads();
    }
    if (i < N) excl[i] = s[t] - v;
    if (t == 255) bsum[blockIdx.x] = s[255];
}

__global__ __launch_bounds__(256) void k_scan2(const int* __restrict__ bsum, int NB,
    int* __restrict__ boff)
{
    __shared__ int s[256];
    int t = threadIdx.x;
    int v = (t < NB) ? bsum[t] : 0;
    s[t] = v; __syncthreads();
#pragma unroll
    for (int o = 1; o < 256; o <<= 1) {
        int x = (t >= o) ? s[t - o] : 0;
        __syncthreads();
        s[t] += x;
        __syncthreads();
    }
    if (t < NB) boff[t] = s[t] - v;
}

__global__ void k_scan3(const int* __restrict__ excl, const int* __restrict__ boff,
    int N, int M, int* __restrict__ rowptr)
{
    int i = blockIdx.x * blockDim.x + threadIdx.x;
    if (i < N) rowptr[i] = excl[i] + boff[i >> 8];
    if (i == 0) rowptr[N] = M;
}

__global__ void k_scatter(const int* __restrict__ ei, int E, int M,
    const int* __restrict__ rowptr, int* __restrict__ cnt, int* __restrict__ csr_src)
{
    int i = blockIdx.x * blockDim.x + threadIdx.x;
    if (i >= M) return;
    int src, dst;
    if (i < E) { src = ei[i]; dst = ei[E + i]; } else { src = i - E; dst = src; }
    int pos = rowptr[dst] + atomicAdd(&cnt[dst], 1);
    csr_src[pos] = src;
}

// ============ Layer 1 fused softmax+aggregate+bias+ELU ============
__global__ __launch_bounds__(128) void k_agg1_fused(const int* __restrict__ rowptr,
    const int* __restrict__ csr_src, const float* __restrict__ a_s1,
    const float* __restrict__ a_d1, const __hip_bfloat16* __restrict__ h1b,
    const float* __restrict__ b1, __hip_bfloat16* __restrict__ h2b)
{
    const int dst = blockIdx.x, t = threadIdx.x;
    const int h = t >> 5;                 // head for cols {2t, 2t+1}
    const int start = rowptr[dst], end = rowptr[dst + 1];
    __shared__ int   s_src[128];
    __shared__ float s_ex[128][4];
    __shared__ float s_part[2][4];
    float4 ad = ((const float4*)a_d1)[dst];
    float d0 = 0.f, d1 = 0.f, d2 = 0.f, d3 = 0.f;
    float accx = 0.f, accy = 0.f;

    for (int base = start; base < end; base += 128) {
        int nloc = end - base; if (nloc > 128) nloc = 128;
        if (t < nloc) {
            int src = csr_src[base + t];
            s_src[t] = src;
            float4 as = ((const float4*)a_s1)[src];
            float e0 = as.x + ad.x; e0 = e0 > 0.f ? e0 : NEG_SLOPE * e0;
            float e1 = as.y + ad.y; e1 = e1 > 0.f ? e1 : NEG_SLOPE * e1;
            float e2 = as.z + ad.z; e2 = e2 > 0.f ? e2 : NEG_SLOPE * e2;
            float e3 = as.w + ad.w; e3 = e3 > 0.f ? e3 : NEG_SLOPE * e3;
            float x0 = expf(e0), x1 = expf(e1), x2 = expf(e2), x3 = expf(e3);
            s_ex[t][0] = x0; s_ex[t][1] = x1; s_ex[t][2] = x2; s_ex[t][3] = x3;
            d0 += x0; d1 += x1; d2 += x2; d3 += x3;
        }
        __syncthreads();
        int j = 0;
        for (; j + 3 < nloc; j += 4) {      // 4 gathers in flight
            const __hip_bfloat162* pA = (const __hip_bfloat162*)(h1b + (size_t)s_src[j]     * 256);
            const __hip_bfloat162* pB = (const __hip_bfloat162*)(h1b + (size_t)s_src[j + 1] * 256);
            const __hip_bfloat162* pC = (const __hip_bfloat162*)(h1b + (size_t)s_src[j + 2] * 256);
            const __hip_bfloat162* pD = (const __hip_bfloat162*)(h1b + (size_t)s_src[j + 3] * 256);
            __hip_bfloat162 vA = pA[t], vB = pB[t], vC = pC[t], vD = pD[t];
            float eA = s_ex[j][h], eB = s_ex[j + 1][h], eC = s_ex[j + 2][h], eD = s_ex[j + 3][h];
            accx += eA * __bfloat162float(vA.x) + eB * __bfloat162float(vB.x)
                  + eC * __bfloat162float(vC.x) + eD * __bfloat162float(vD.x);
            accy += eA * __bfloat162float(vA.y) + eB * __bfloat162float(vB.y)
                  + eC * __bfloat162float(vC.y) + eD * __bfloat162float(vD.y);
        }
        for (; j < nloc; ++j) {
            const __hip_bfloat162* pA = (const __hip_bfloat162*)(h1b + (size_t)s_src[j] * 256);
            __hip_bfloat162 vA = pA[t];
            float eA = s_ex[j][h];
            accx += eA * __bfloat162float(vA.x);
            accy += eA * __bfloat162float(vA.y);
        }
        __syncthreads();
    }
#pragma unroll
    for (int o = 32; o > 0; o >>= 1) {
        d0 += __shfl_down(d0, o); d1 += __shfl_down(d1, o);
        d2 += __shfl_down(d2, o); d3 += __shfl_down(d3, o);
    }
    if ((t & 63) == 0) {
        int wv = t >> 6;
        s_part[wv][0] = d0; s_part[wv][1] = d1; s_part[wv][2] = d2; s_part[wv][3] = d3;
    }
    __syncthreads();
    float inv = 1.0f / (s_part[0][h] + s_part[1][h]);
    float2 bb = ((const float2*)b1)[t];
    float v0 = accx * inv + bb.x; v0 = v0 > 0.f ? v0 : (expf(v0) - 1.f);
    float v1 = accy * inv + bb.y; v1 = v1 > 0.f ? v1 : (expf(v1) - 1.f);
    __hip_bfloat162 o2; o2.x = __float2bfloat16(v0); o2.y = __float2bfloat16(v1);
    ((__hip_bfloat162*)(h2b + (size_t)dst * 256))[t] = o2;
}

// ============ Layer 2 GEMM: (N,256)x(256,64), 16 rows/block, 4 waves x 4 rows ====
// h2 rows are wave-uniform -> scalar loads; bf16->fp32 decode via uniform
// shift/mask (scalar pipe, free). Inner loop pure v_fma_f32(v, s, v). No LDS.
__global__ __launch_bounds__(256) void k_gemm2_att(
    const __hip_bfloat16* __restrict__ h2b, const float* __restrict__ W2,
    const float* __restrict__ as2, const float* __restrict__ ad2,
    __hip_bfloat16* __restrict__ h3b, float* __restrict__ a_s2, float* __restrict__ a_d2)
{
    const int n0 = blockIdx.x * 16, t = threadIdx.x;
    const int col = t & 63, wv = t >> 6;
    const int r0 = n0 + wv * 4;
    const unsigned* __restrict__ hu = (const unsigned*)h2b + (size_t)r0 * 128; // 128 dwords/row
    float acc[4] = {0.f, 0.f, 0.f, 0.f};
#pragma unroll 2
    for (int kd = 0; kd < 128; kd += 2) {  // 2 dwords = 4 k values
        float w0 = W2[(2 * kd + 0) * 64 + col];
        float w1 = W2[(2 * kd + 1) * 64 + col];
        float w2 = W2[(2 * kd + 2) * 64 + col];
        float w3 = W2[(2 * kd + 3) * 64 + col];
#pragma unroll
        for (int r = 0; r < 4; ++r) {
            unsigned ua = hu[r * 128 + kd], ub = hu[r * 128 + kd + 1];
            acc[r] += __uint_as_float(ua << 16) * w0
                    + __uint_as_float(ua & 0xffff0000u) * w1
                    + __uint_as_float(ub << 16) * w2
                    + __uint_as_float(ub & 0xffff0000u) * w3;
        }
    }
    float vas = as2[col], vad = ad2[col];
#pragma unroll
    for (int r = 0; r < 4; ++r) {
        h3b[(size_t)(r0 + r) * 64 + col] = __float2bfloat16(acc[r]);
        float s = acc[r] * vas, d = acc[r] * vad;
#pragma unroll
        for (int o = 32; o > 0; o >>= 1) { s += __shfl_down(s, o); d += __shfl_down(d, o); }
        if (col == 0) { a_s2[r0 + r] = s; a_d2[r0 + r] = d; }
    }
}

// ============ Layer 2 fused softmax+aggregate + b2 -> out ============
__global__ __launch_bounds__(64) void k_agg2_fused(const int* __restrict__ rowptr,
    const int* __restrict__ csr_src, const float* __restrict__ a_s2,
    const float* __restrict__ a_d2, const __hip_bfloat16* __restrict__ h3b,
    const float* __restrict__ b2, float* __restrict__ out)
{
    const int dst = blockIdx.x, t = threadIdx.x;
    const int start = rowptr[dst], end = rowptr[dst + 1];
    __shared__ int   s_src[64];
    __shared__ float s_ex[64];
    float ad = a_d2[dst];
    float den = 0.f, acc = 0.f;

    for (int base = start; base < end; base += 64) {
        int nloc = end - base; if (nloc > 64) nloc = 64;
        if (t < nloc) {
            int src = csr_src[base + t];
            s_src[t] = src;
            float e = a_s2[src] + ad;
            e = e > 0.f ? e : NEG_SLOPE * e;
            float ex = expf(e);
            s_ex[t] = ex;
            den += ex;
        }
        __syncthreads();
        int j = 0;
        for (; j + 3 < nloc; j += 4) {
            float vA = __bfloat162float(h3b[(size_t)s_src[j]     * 64 + t]);
            float vB = __bfloat162float(h3b[(size_t)s_src[j + 1] * 64 + t]);
            float vC = __bfloat162float(h3b[(size_t)s_src[j + 2] * 64 + t]);
            float vD = __bfloat162float(h3b[(size_t)s_src[j + 3] * 64 + t]);
            acc += s_ex[j] * vA + s_ex[j + 1] * vB + s_ex[j + 2] * vC + s_ex[j + 3] * vD;
        }
        for (; j < nloc; ++j)
            acc += s_ex[j] * __bfloat162float(h3b[(size_t)s_src[j] * 64 + t]);
        __syncthreads();
    }
#pragma unroll
    for (int o = 1; o < 64; o <<= 1) den += __shfl_xor(den, o);
    out[(size_t)dst * 64 + t] = acc / den + b2[t];
}

extern "C" void kernel_launch(void* const* d_in, const int* in_sizes, int n_in,
                              void* d_out, int out_size, void* d_ws, size_t ws_size,
                              hipStream_t stream)
{
    const float* x   = (const float*)d_in[0];
    const int*   ei  = (const int*)d_in[1];
    const float* W1  = (const float*)d_in[2];
    const float* as1 = (const float*)d_in[3];
    const float* ad1 = (const float*)d_in[4];
    const float* b1  = (const float*)d_in[5];
    const float* W2  = (const float*)d_in[6];
    const float* as2 = (const float*)d_in[7];
    const float* ad2 = (const float*)d_in[8];
    const float* b2  = (const float*)d_in[9];
    float* out = (float*)d_out;

    const int N = in_sizes[0] / 128;      // 50000
    const int E = in_sizes[1] / 2;        // 800000
    const int M = E + N;                  // edges + self loops
    const int NB = (N + 255) / 256;       // scan blocks

    // ---- workspace layout (256B-aligned), ~63 MB ----
    char* w = (char*)d_ws;
    size_t o = 0;
    auto alloc = [&](size_t bytes) { size_t r = o; o = (o + bytes + 255) & ~(size_t)255; return r; };
    __hip_bfloat16* h1b   = (__hip_bfloat16*)(w + alloc((size_t)N * 256 * 2)); // 25.6 MB
    float* a_s1           = (float*)(w + alloc((size_t)N * 4 * 4));
    float* a_d1           = (float*)(w + alloc((size_t)N * 4 * 4));
    __hip_bfloat16* h2b   = (__hip_bfloat16*)(w + alloc((size_t)N * 256 * 2)); // 25.6 MB
    __hip_bfloat16* h3b   = (__hip_bfloat16*)(w + alloc((size_t)N * 64 * 2));  // 6.4 MB
    float* a_s2           = (float*)(w + alloc((size_t)N * 4));
    float* a_d2           = (float*)(w + alloc((size_t)N * 4));
    int* deg              = (int*)(w + alloc((size_t)N * 4));
    int* cnt              = (int*)(w + alloc((size_t)N * 4));
    int* rowptr           = (int*)(w + alloc((size_t)(N + 1) * 4));
    int* excl             = (int*)(w + alloc((size_t)N * 4));
    int* bsum             = (int*)(w + alloc((size_t)NB * 4));
    int* boff             = (int*)(w + alloc((size_t)NB * 4));
    int* csr_src          = (int*)(w + alloc((size_t)M * 4));                  // 3.4 MB

    // ---- CSR build (shared by both layers) ----
    hipMemsetAsync(deg, 0, (size_t)N * 4, stream);
    hipMemsetAsync(cnt, 0, (size_t)N * 4, stream);
    k_hist<<<(M + 255) / 256, 256, 0, stream>>>(ei, E, M, deg);
    k_scan1<<<NB, 256, 0, stream>>>(deg, N, excl, bsum);
    k_scan2<<<1, 256, 0, stream>>>(bsum, NB, boff);
    k_scan3<<<NB, 256, 0, stream>>>(excl, boff, N, M, rowptr);
    k_scatter<<<(M + 255) / 256, 256, 0, stream>>>(ei, E, M, rowptr, cnt, csr_src);

    // ---- layer 1 ----
    k_gemm1_att<<<N / 16, 256, 0, stream>>>(x, W1, as1, ad1, h1b, a_s1, a_d1);
    k_agg1_fused<<<N, 128, 0, stream>>>(rowptr, csr_src, a_s1, a_d1, h1b, b1, h2b);

    // ---- layer 2 ----
    k_gemm2_att<<<N / 16, 256, 0, stream>>>(h2b, W2, as2, ad2, h3b, a_s2, a_d2);
    k_agg2_fused<<<N, 64, 0, stream>>>(rowptr, csr_src, a_s2, a_d2, h3b, b2, out);
}

// Round 6
// 393.747 us; speedup vs baseline: 1.1864x; 1.1864x over previous
//
#include <hip/hip_runtime.h>
#include <hip/hip_bf16.h>

#define NEG_SLOPE 0.2f

__device__ __forceinline__ float bflo(unsigned u) { return __uint_as_float(u << 16); }
__device__ __forceinline__ float bfhi(unsigned u) { return __uint_as_float(u & 0xffff0000u); }

// ============ Layer 1 GEMM: (N,128)x(128,256), 16 rows/block, 2 cols/thread ====
// Thread t: cols {c, c+128} (c=t&127), row-group rg=t>>7 covers 8 rows.
// Per k-step-of-4: 1 ds_read_b128 per row (wave-broadcast) feeds 8 FMAs.
__global__ __launch_bounds__(256) void k_gemm1_att(
    const float* __restrict__ x, const float* __restrict__ W1,
    const float* __restrict__ as1, const float* __restrict__ ad1,
    __hip_bfloat16* __restrict__ h1b, float* __restrict__ a_s1, float* __restrict__ a_d1,
    int N)
{
    const int n0 = blockIdx.x * 16, t = threadIdx.x;
    const int c = t & 127, rg = t >> 7;
    __shared__ float xs[16 * 128];
    {
        const int nrows = (N - n0 < 16) ? (N - n0) : 16;
        const float4* xv = (const float4*)(x + (size_t)n0 * 128);
        float4* s4 = (float4*)xs;
        const int tot = nrows * 32;           // float4s to stage
        if (t < tot) s4[t] = xv[t];
        if (t + 256 < tot) s4[t + 256] = xv[t + 256];
    }
    __syncthreads();
    float acc0[8], acc1[8];
#pragma unroll
    for (int r = 0; r < 8; ++r) { acc0[r] = 0.f; acc1[r] = 0.f; }
    const float4* xs4 = (const float4*)xs;    // xs4[row*32 + kb]
#pragma unroll 2
    for (int kb = 0; kb < 32; ++kb) {
        float w00 = W1[(4 * kb + 0) * 256 + c];
        float w01 = W1[(4 * kb + 1) * 256 + c];
        float w02 = W1[(4 * kb + 2) * 256 + c];
        float w03 = W1[(4 * kb + 3) * 256 + c];
        float w10 = W1[(4 * kb + 0) * 256 + c + 128];
        float w11 = W1[(4 * kb + 1) * 256 + c + 128];
        float w12 = W1[(4 * kb + 2) * 256 + c + 128];
        float w13 = W1[(4 * kb + 3) * 256 + c + 128];
#pragma unroll
        for (int r = 0; r < 8; ++r) {
            float4 xv = xs4[(rg * 8 + r) * 32 + kb];
            acc0[r] += xv.x * w00 + xv.y * w01 + xv.z * w02 + xv.w * w03;
            acc1[r] += xv.x * w10 + xv.y * w11 + xv.z * w12 + xv.w * w13;
        }
    }
    float vas0 = as1[c], vad0 = ad1[c], vas1 = as1[c + 128], vad1 = ad1[c + 128];
    const int h0 = (t >> 6) & 1;              // wave-uniform head of col c
#pragma unroll
    for (int r = 0; r < 8; ++r) {
        int row = n0 + rg * 8 + r;
        if (row < N) {
            h1b[(size_t)row * 256 + c]       = __float2bfloat16(acc0[r]);
            h1b[(size_t)row * 256 + c + 128] = __float2bfloat16(acc1[r]);
        }
        float s0 = acc0[r] * vas0, d0 = acc0[r] * vad0;
        float s1 = acc1[r] * vas1, d1 = acc1[r] * vad1;
#pragma unroll
        for (int o = 32; o > 0; o >>= 1) {
            s0 += __shfl_down(s0, o); d0 += __shfl_down(d0, o);
            s1 += __shfl_down(s1, o); d1 += __shfl_down(d1, o);
        }
        if ((t & 63) == 0 && row < N) {
            a_s1[row * 4 + h0]     = s0; a_d1[row * 4 + h0]     = d0;
            a_s1[row * 4 + h0 + 2] = s1; a_d1[row * 4 + h0 + 2] = d1;
        }
    }
}

// ============ CSR build ============
__global__ void k_hist(const int* __restrict__ ei, int E, int M, int* __restrict__ deg)
{
    int i = blockIdx.x * blockDim.x + threadIdx.x;
    if (i >= M) return;
    int dst = (i < E) ? ei[E + i] : (i - E);
    atomicAdd(&deg[dst], 1);
}

__global__ __launch_bounds__(256) void k_scan1(const int* __restrict__ deg, int N,
    int* __restrict__ excl, int* __restrict__ bsum)
{
    __shared__ int s[256];
    int t = threadIdx.x, i = blockIdx.x * 256 + t;
    int v = (i < N) ? deg[i] : 0;
    s[t] = v; __syncthreads();
#pragma unroll
    for (int o = 1; o < 256; o <<= 1) {
        int x = (t >= o) ? s[t - o] : 0;
        __syncthreads();
        s[t] += x;
        __syncthreads();
    }
    if (i < N) excl[i] = s[t] - v;
    if (t == 255) bsum[blockIdx.x] = s[255];
}

__global__ __launch_bounds__(256) void k_scan2(const int* __restrict__ bsum, int NB,
    int* __restrict__ boff)
{
    __shared__ int s[256];
    int t = threadIdx.x;
    int v = (t < NB) ? bsum[t] : 0;
    s[t] = v; __syncthreads();
#pragma unroll
    for (int o = 1; o < 256; o <<= 1) {
        int x = (t >= o) ? s[t - o] : 0;
        __syncthreads();
        s[t] += x;
        __syncthreads();
    }
    if (t < NB) boff[t] = s[t] - v;
}

__global__ void k_scan3(const int* __restrict__ excl, const int* __restrict__ boff,
    int N, int M, int* __restrict__ rowptr)
{
    int i = blockIdx.x * blockDim.x + threadIdx.x;
    if (i < N) rowptr[i] = excl[i] + boff[i >> 8];
    if (i == 0) rowptr[N] = M;
}

__global__ void k_scatter(const int* __restrict__ ei, int E, int M,
    const int* __restrict__ rowptr, int* __restrict__ cnt, int* __restrict__ csr_src)
{
    int i = blockIdx.x * blockDim.x + threadIdx.x;
    if (i >= M) return;
    int src, dst;
    if (i < E) { src = ei[i]; dst = ei[E + i]; } else { src = i - E; dst = src; }
    int pos = rowptr[dst] + atomicAdd(&cnt[dst], 1);
    csr_src[pos] = src;
}

// ============ Layer 1 fused softmax+aggregate+bias+ELU ============
// 1 wave per dst. Lane t: cols {4t..4t+3} via uint2 (512B/row per wave-instr),
// head h=t>>4. 8 gathers in flight. Unnormalized sum; divide at end.
__global__ __launch_bounds__(64) void k_agg1_fused(const int* __restrict__ rowptr,
    const int* __restrict__ csr_src, const float* __restrict__ a_s1,
    const float* __restrict__ a_d1, const __hip_bfloat16* __restrict__ h1b,
    const float* __restrict__ b1, __hip_bfloat16* __restrict__ h2b)
{
    const int dst = blockIdx.x, t = threadIdx.x;
    const int h = t >> 4;
    const int start = rowptr[dst], end = rowptr[dst + 1];
    __shared__ int   s_src[64];
    __shared__ float s_ex[64][4];
    float4 ad = ((const float4*)a_d1)[dst];
    float d0 = 0.f, d1 = 0.f, d2 = 0.f, d3 = 0.f;
    float a0 = 0.f, a1 = 0.f, a2 = 0.f, a3 = 0.f;

    for (int base = start; base < end; base += 64) {
        int nloc = end - base; if (nloc > 64) nloc = 64;
        if (t < nloc) {
            int src = csr_src[base + t];
            s_src[t] = src;
            float4 as = ((const float4*)a_s1)[src];
            float e0 = as.x + ad.x; e0 = e0 > 0.f ? e0 : NEG_SLOPE * e0;
            float e1 = as.y + ad.y; e1 = e1 > 0.f ? e1 : NEG_SLOPE * e1;
            float e2 = as.z + ad.z; e2 = e2 > 0.f ? e2 : NEG_SLOPE * e2;
            float e3 = as.w + ad.w; e3 = e3 > 0.f ? e3 : NEG_SLOPE * e3;
            float x0 = expf(e0), x1 = expf(e1), x2 = expf(e2), x3 = expf(e3);
            s_ex[t][0] = x0; s_ex[t][1] = x1; s_ex[t][2] = x2; s_ex[t][3] = x3;
            d0 += x0; d1 += x1; d2 += x2; d3 += x3;
        }
        __syncthreads();
        int j = 0;
        for (; j + 7 < nloc; j += 8) {
            uint2 v[8];
#pragma unroll
            for (int q = 0; q < 8; ++q)
                v[q] = ((const uint2*)(h1b + (size_t)s_src[j + q] * 256))[t];
#pragma unroll
            for (int q = 0; q < 8; ++q) {
                float e = s_ex[j + q][h];
                a0 += e * bflo(v[q].x); a1 += e * bfhi(v[q].x);
                a2 += e * bflo(v[q].y); a3 += e * bfhi(v[q].y);
            }
        }
        for (; j < nloc; ++j) {
            uint2 v = ((const uint2*)(h1b + (size_t)s_src[j] * 256))[t];
            float e = s_ex[j][h];
            a0 += e * bflo(v.x); a1 += e * bfhi(v.x);
            a2 += e * bflo(v.y); a3 += e * bfhi(v.y);
        }
        __syncthreads();
    }
#pragma unroll
    for (int o = 32; o > 0; o >>= 1) {   // butterfly: all lanes get totals
        d0 += __shfl_xor(d0, o); d1 += __shfl_xor(d1, o);
        d2 += __shfl_xor(d2, o); d3 += __shfl_xor(d3, o);
    }
    float den = (h == 0) ? d0 : (h == 1) ? d1 : (h == 2) ? d2 : d3;
    float inv = 1.0f / den;
    float4 bb = ((const float4*)b1)[t];
    float v0 = a0 * inv + bb.x; v0 = v0 > 0.f ? v0 : (expf(v0) - 1.f);
    float v1 = a1 * inv + bb.y; v1 = v1 > 0.f ? v1 : (expf(v1) - 1.f);
    float v2 = a2 * inv + bb.z; v2 = v2 > 0.f ? v2 : (expf(v2) - 1.f);
    float v3 = a3 * inv + bb.w; v3 = v3 > 0.f ? v3 : (expf(v3) - 1.f);
    __hip_bfloat162 p0, p1;
    p0.x = __float2bfloat16(v0); p0.y = __float2bfloat16(v1);
    p1.x = __float2bfloat16(v2); p1.y = __float2bfloat16(v3);
    __hip_bfloat162* op = (__hip_bfloat162*)(h2b + (size_t)dst * 256);
    op[2 * t] = p0; op[2 * t + 1] = p1;
}

// ============ Layer 2 GEMM: (N,256)x(256,64), 32 rows/block ============
// Thread t: col=t&63, row-group rg=t>>6 covers 8 rows. fp32 LDS tile,
// wave-broadcast b128 reads (no bank conflicts).
__global__ __launch_bounds__(256) void k_gemm2_att(
    const __hip_bfloat16* __restrict__ h2b, const float* __restrict__ W2,
    const float* __restrict__ as2, const float* __restrict__ ad2,
    __hip_bfloat16* __restrict__ h3b, float* __restrict__ a_s2, float* __restrict__ a_d2,
    int N)
{
    const int n0 = blockIdx.x * 32, t = threadIdx.x;
    const int col = t & 63, rg = t >> 6;
    __shared__ float hs[32 * 256];        // 32 KB
    {
        const int nrows = (N - n0 < 32) ? (N - n0) : 32;
        const unsigned* hu = (const unsigned*)(h2b + (size_t)n0 * 256);
        const int tot = nrows * 128;      // dwords
        for (int i = t; i < tot; i += 256) {
            unsigned u = hu[i];
            hs[2 * i]     = bflo(u);
            hs[2 * i + 1] = bfhi(u);
        }
    }
    __syncthreads();
    float acc[8];
#pragma unroll
    for (int r = 0; r < 8; ++r) acc[r] = 0.f;
    const float4* hs4 = (const float4*)hs;   // hs4[row*64 + kb]
#pragma unroll 2
    for (int kb = 0; kb < 64; ++kb) {
        float w0 = W2[(4 * kb + 0) * 64 + col];
        float w1 = W2[(4 * kb + 1) * 64 + col];
        float w2 = W2[(4 * kb + 2) * 64 + col];
        float w3 = W2[(4 * kb + 3) * 64 + col];
#pragma unroll
        for (int r = 0; r < 8; ++r) {
            float4 hv = hs4[(rg * 8 + r) * 64 + kb];
            acc[r] += hv.x * w0 + hv.y * w1 + hv.z * w2 + hv.w * w3;
        }
    }
    float vas = as2[col], vad = ad2[col];
#pragma unroll
    for (int r = 0; r < 8; ++r) {
        int row = n0 + rg * 8 + r;
        if (row < N) h3b[(size_t)row * 64 + col] = __float2bfloat16(acc[r]);
        float s = acc[r] * vas, d = acc[r] * vad;
#pragma unroll
        for (int o = 32; o > 0; o >>= 1) { s += __shfl_down(s, o); d += __shfl_down(d, o); }
        if ((t & 63) == 0 && row < N) { a_s2[row] = s; a_d2[row] = d; }
    }
}

// ============ Layer 2 fused softmax+aggregate + b2 -> out ============
// 2 dsts/block (one per 32-lane half), dword gathers (cols 2l,2l+1), 8-wide ILP.
// Chunk loop count uniformized across the wave to keep __syncthreads legal.
__global__ __launch_bounds__(64) void k_agg2_fused(const int* __restrict__ rowptr,
    const int* __restrict__ csr_src, const float* __restrict__ a_s2,
    const float* __restrict__ a_d2, const __hip_bfloat16* __restrict__ h3b,
    const float* __restrict__ b2, float* __restrict__ out, int N)
{
    const int t = threadIdx.x, half = t >> 5, l = t & 31;
    const int dst = blockIdx.x * 2 + half;
    const bool valid = dst < N;
    int start = 0, end = 0;
    float adv = 0.f;
    if (valid) { start = rowptr[dst]; end = rowptr[dst + 1]; adv = a_d2[dst]; }
    int trips = (end - start + 31) >> 5;
#pragma unroll
    for (int o = 32; o > 0; o >>= 1) { int u = __shfl_xor(trips, o); trips = u > trips ? u : trips; }
    __shared__ int   s_src[2][32];
    __shared__ float s_ex[2][32];
    float den = 0.f, acc0 = 0.f, acc1 = 0.f;

    for (int it = 0; it < trips; ++it) {
        int base = start + it * 32;
        int nloc = end - base; if (nloc > 32) nloc = 32; if (nloc < 0) nloc = 0;
        if (l < nloc) {
            int src = csr_src[base + l];
            s_src[half][l] = src;
            float e = a_s2[src] + adv;
            e = e > 0.f ? e : NEG_SLOPE * e;
            float ex = expf(e);
            s_ex[half][l] = ex;
            den += ex;
        }
        __syncthreads();
        int j = 0;
        for (; j + 7 < nloc; j += 8) {
            unsigned v[8];
#pragma unroll
            for (int q = 0; q < 8; ++q)
                v[q] = ((const unsigned*)(h3b + (size_t)s_src[half][j + q] * 64))[l];
#pragma unroll
            for (int q = 0; q < 8; ++q) {
                float e = s_ex[half][j + q];
                acc0 += e * bflo(v[q]); acc1 += e * bfhi(v[q]);
            }
        }
        for (; j < nloc; ++j) {
            unsigned v = ((const unsigned*)(h3b + (size_t)s_src[half][j] * 64))[l];
            float e = s_ex[half][j];
            acc0 += e * bflo(v); acc1 += e * bfhi(v);
        }
        __syncthreads();
    }
#pragma unroll
    for (int o = 16; o > 0; o >>= 1) den += __shfl_xor(den, o);  // within 32-lane half
    if (valid) {
        float inv = 1.0f / den;
        float2 bb = ((const float2*)b2)[l];
        float2 ov; ov.x = acc0 * inv + bb.x; ov.y = acc1 * inv + bb.y;
        ((float2*)(out + (size_t)dst * 64))[l] = ov;
    }
}

extern "C" void kernel_launch(void* const* d_in, const int* in_sizes, int n_in,
                              void* d_out, int out_size, void* d_ws, size_t ws_size,
                              hipStream_t stream)
{
    const float* x   = (const float*)d_in[0];
    const int*   ei  = (const int*)d_in[1];
    const float* W1  = (const float*)d_in[2];
    const float* as1 = (const float*)d_in[3];
    const float* ad1 = (const float*)d_in[4];
    const float* b1  = (const float*)d_in[5];
    const float* W2  = (const float*)d_in[6];
    const float* as2 = (const float*)d_in[7];
    const float* ad2 = (const float*)d_in[8];
    const float* b2  = (const float*)d_in[9];
    float* out = (float*)d_out;

    const int N = in_sizes[0] / 128;      // 50000
    const int E = in_sizes[1] / 2;        // 800000
    const int M = E + N;                  // edges + self loops
    const int NB = (N + 255) / 256;       // scan blocks

    // ---- workspace layout (256B-aligned), ~63 MB ----
    char* w = (char*)d_ws;
    size_t o = 0;
    auto alloc = [&](size_t bytes) { size_t r = o; o = (o + bytes + 255) & ~(size_t)255; return r; };
    __hip_bfloat16* h1b   = (__hip_bfloat16*)(w + alloc((size_t)N * 256 * 2)); // 25.6 MB
    float* a_s1           = (float*)(w + alloc((size_t)N * 4 * 4));
    float* a_d1           = (float*)(w + alloc((size_t)N * 4 * 4));
    __hip_bfloat16* h2b   = (__hip_bfloat16*)(w + alloc((size_t)N * 256 * 2)); // 25.6 MB
    __hip_bfloat16* h3b   = (__hip_bfloat16*)(w + alloc((size_t)N * 64 * 2));  // 6.4 MB
    float* a_s2           = (float*)(w + alloc((size_t)N * 4));
    float* a_d2           = (float*)(w + alloc((size_t)N * 4));
    int* deg              = (int*)(w + alloc((size_t)N * 4));
    int* cnt              = (int*)(w + alloc((size_t)N * 4));
    int* rowptr           = (int*)(w + alloc((size_t)(N + 1) * 4));
    int* excl             = (int*)(w + alloc((size_t)N * 4));
    int* bsum             = (int*)(w + alloc((size_t)NB * 4));
    int* boff             = (int*)(w + alloc((size_t)NB * 4));
    int* csr_src          = (int*)(w + alloc((size_t)M * 4));                  // 3.4 MB

    // ---- CSR build (shared by both layers) ----
    hipMemsetAsync(deg, 0, (size_t)N * 4, stream);
    hipMemsetAsync(cnt, 0, (size_t)N * 4, stream);
    k_hist<<<(M + 255) / 256, 256, 0, stream>>>(ei, E, M, deg);
    k_scan1<<<NB, 256, 0, stream>>>(deg, N, excl, bsum);
    k_scan2<<<1, 256, 0, stream>>>(bsum, NB, boff);
    k_scan3<<<NB, 256, 0, stream>>>(excl, boff, N, M, rowptr);
    k_scatter<<<(M + 255) / 256, 256, 0, stream>>>(ei, E, M, rowptr, cnt, csr_src);

    // ---- layer 1 ----
    k_gemm1_att<<<(N + 15) / 16, 256, 0, stream>>>(x, W1, as1, ad1, h1b, a_s1, a_d1, N);
    k_agg1_fused<<<N, 64, 0, stream>>>(rowptr, csr_src, a_s1, a_d1, h1b, b1, h2b);

    // ---- layer 2 ----
    k_gemm2_att<<<(N + 31) / 32, 256, 0, stream>>>(h2b, W2, as2, ad2, h3b, a_s2, a_d2, N);
    k_agg2_fused<<<(N + 1) / 2, 64, 0, stream>>>(rowptr, csr_src, a_s2, a_d2, h3b, b2, out, N);
}

// Round 7
// 346.523 us; speedup vs baseline: 1.3481x; 1.1363x over previous
//
#include <hip/hip_runtime.h>
#include <hip/hip_bf16.h>

#define NEG_SLOPE 0.2f

typedef __attribute__((ext_vector_type(8))) short short8;   // 8 bf16 (4 VGPRs)
typedef __attribute__((ext_vector_type(4))) float f32x4;    // MFMA accumulator

__device__ __forceinline__ float bflo(unsigned u) { return __uint_as_float(u << 16); }
__device__ __forceinline__ float bfhi(unsigned u) { return __uint_as_float(u & 0xffff0000u); }
__device__ __forceinline__ unsigned pk2bf(float a, float b) {
    __hip_bfloat162 t; t.x = __float2bfloat16(a); t.y = __float2bfloat16(b);
    return *reinterpret_cast<unsigned*>(&t);
}

#define KP 136   // padded k-stride (elements) for MFMA LDS tiles

// ============ prep: W1 fp32 [k=128][n=256] -> W1t bf16 [n][k] padded KP ============
__global__ void k_prepW1(const float* __restrict__ W1, __hip_bfloat16* __restrict__ W1t)
{
    int i = blockIdx.x * 256 + threadIdx.x;       // 256*KP total
    if (i >= 256 * KP) return;
    int n = i / KP, k = i % KP;
    float v = (k < 128) ? W1[k * 256 + n] : 0.f;
    W1t[i] = __float2bfloat16(v);
}

// ============ Layer 1 GEMM via MFMA: (N,128)x(128,256) bf16, fp32 acc ============
// Block: 64 rows x 128 cols (blockIdx.y = col half). 4 waves x 16-row strips.
// A-frag: A[m=lane&15][k=quad*8+j]; B-frag: B[k=quad*8+j][n=lane&15];
// D: row=quad*4+reg, col=lane&15 (m89/m101-verified layouts).
__global__ __launch_bounds__(256) void k_gemm1_mfma(
    const float* __restrict__ x, const __hip_bfloat16* __restrict__ W1t,
    __hip_bfloat16* __restrict__ h1b, int N)
{
    const int n0 = blockIdx.x * 64;
    const int c0 = blockIdx.y * 128;
    const int t = threadIdx.x, wv = t >> 6, lane = t & 63;
    const int l15 = lane & 15, q = lane >> 4;

    __shared__ short sA[64 * KP];    // 17408 B
    __shared__ short sB[128 * KP];   // 34816 B

    // stage A: x fp32 -> bf16, row-major stride KP, zero-fill OOB rows
    {
        const float4* x4 = (const float4*)x;
        for (int i = t; i < 2048; i += 256) {       // 64 rows * 32 float4
            int row = i >> 5, kq = i & 31;
            float4 v = make_float4(0.f, 0.f, 0.f, 0.f);
            if (n0 + row < N) v = x4[(size_t)(n0 + row) * 32 + kq];
            uint2 p; p.x = pk2bf(v.x, v.y); p.y = pk2bf(v.z, v.w);
            *(uint2*)(sA + row * KP + kq * 4) = p;
        }
    }
    // stage B: contiguous copy of this block's col-half of W1t
    {
        const uint4* src = (const uint4*)((const short*)W1t + (size_t)c0 * KP);
        uint4* dst = (uint4*)sB;
        for (int i = t; i < (128 * KP * 2) / 16; i += 256) dst[i] = src[i];
    }
    __syncthreads();

    // A-frags for this wave's 16-row strip (held across col loop)
    short8 af[4];
#pragma unroll
    for (int kc = 0; kc < 4; ++kc)
        af[kc] = *(const short8*)(sA + (wv * 16 + l15) * KP + kc * 32 + q * 8);

    f32x4 acc[8];
#pragma unroll
    for (int nt = 0; nt < 8; ++nt) {
        f32x4 a = {0.f, 0.f, 0.f, 0.f};
#pragma unroll
        for (int kc = 0; kc < 4; ++kc) {
            short8 bf = *(const short8*)(sB + (nt * 16 + l15) * KP + kc * 32 + q * 8);
            a = __builtin_amdgcn_mfma_f32_16x16x32_bf16(af[kc], bf, a, 0, 0, 0);
        }
        acc[nt] = a;
    }

    // epilogue: store h1 (row=quad*4+reg, col=lane&15)
#pragma unroll
    for (int nt = 0; nt < 8; ++nt) {
#pragma unroll
        for (int r = 0; r < 4; ++r) {
            int row = n0 + wv * 16 + q * 4 + r;
            if (row < N)
                h1b[(size_t)row * 256 + c0 + nt * 16 + l15] = __float2bfloat16(acc[nt][r]);
        }
    }
}

// ============ att dots: a_s1[n,h] = sum_c h1[n,c]*as1[c] (4 nodes/block) ============
__global__ __launch_bounds__(256) void k_att1(const __hip_bfloat16* __restrict__ h1b,
    const float* __restrict__ as1, const float* __restrict__ ad1,
    float* __restrict__ a_s1, float* __restrict__ a_d1, int N)
{
    const int t = threadIdx.x, lane = t & 63;
    const int node = blockIdx.x * 4 + (t >> 6);
    if (node >= N) return;
    uint2 v = ((const uint2*)(h1b + (size_t)node * 256))[lane];   // cols 4l..4l+3
    float4 as = ((const float4*)as1)[lane];
    float4 ad = ((const float4*)ad1)[lane];
    float ps = bflo(v.x) * as.x + bfhi(v.x) * as.y + bflo(v.y) * as.z + bfhi(v.y) * as.w;
    float pd = bflo(v.x) * ad.x + bfhi(v.x) * ad.y + bflo(v.y) * ad.z + bfhi(v.y) * ad.w;
#pragma unroll
    for (int o = 1; o < 16; o <<= 1) { ps += __shfl_xor(ps, o); pd += __shfl_xor(pd, o); }
    if ((lane & 15) == 0) {
        int h = lane >> 4;
        a_s1[node * 4 + h] = ps; a_d1[node * 4 + h] = pd;
    }
}

// ============ CSR build ============
__global__ void k_hist(const int* __restrict__ ei, int E, int M, int* __restrict__ deg)
{
    int i = blockIdx.x * blockDim.x + threadIdx.x;
    if (i >= M) return;
    int dst = (i < E) ? ei[E + i] : (i - E);
    atomicAdd(&deg[dst], 1);
}

__global__ __launch_bounds__(256) void k_scan1(const int* __restrict__ deg, int N,
    int* __restrict__ excl, int* __restrict__ bsum)
{
    __shared__ int s[256];
    int t = threadIdx.x, i = blockIdx.x * 256 + t;
    int v = (i < N) ? deg[i] : 0;
    s[t] = v; __syncthreads();
#pragma unroll
    for (int o = 1; o < 256; o <<= 1) {
        int x = (t >= o) ? s[t - o] : 0;
        __syncthreads();
        s[t] += x;
        __syncthreads();
    }
    if (i < N) excl[i] = s[t] - v;
    if (t == 255) bsum[blockIdx.x] = s[255];
}

__global__ __launch_bounds__(256) void k_scan2(const int* __restrict__ bsum, int NB,
    int* __restrict__ boff)
{
    __shared__ int s[256];
    int t = threadIdx.x;
    int v = (t < NB) ? bsum[t] : 0;
    s[t] = v; __syncthreads();
#pragma unroll
    for (int o = 1; o < 256; o <<= 1) {
        int x = (t >= o) ? s[t - o] : 0;
        __syncthreads();
        s[t] += x;
        __syncthreads();
    }
    if (t < NB) boff[t] = s[t] - v;
}

__global__ void k_scan3(const int* __restrict__ excl, const int* __restrict__ boff,
    int N, int M, int* __restrict__ rowptr)
{
    int i = blockIdx.x * blockDim.x + threadIdx.x;
    if (i < N) rowptr[i] = excl[i] + boff[i >> 8];
    if (i == 0) rowptr[N] = M;
}

__global__ void k_scatter(const int* __restrict__ ei, int E, int M,
    const int* __restrict__ rowptr, int* __restrict__ cnt, int* __restrict__ csr_src)
{
    int i = blockIdx.x * blockDim.x + threadIdx.x;
    if (i >= M) return;
    int src, dst;
    if (i < E) { src = ei[i]; dst = ei[E + i]; } else { src = i - E; dst = src; }
    int pos = rowptr[dst] + atomicAdd(&cnt[dst], 1);
    csr_src[pos] = src;
}

// ============ Layer 1 fused softmax+aggregate+bias+ELU ============
__global__ __launch_bounds__(64) void k_agg1_fused(const int* __restrict__ rowptr,
    const int* __restrict__ csr_src, const float* __restrict__ a_s1,
    const float* __restrict__ a_d1, const __hip_bfloat16* __restrict__ h1b,
    const float* __restrict__ b1, __hip_bfloat16* __restrict__ h2b)
{
    const int dst = blockIdx.x, t = threadIdx.x;
    const int h = t >> 4;
    const int start = rowptr[dst], end = rowptr[dst + 1];
    __shared__ int   s_src[64];
    __shared__ float s_ex[64][4];
    float4 ad = ((const float4*)a_d1)[dst];
    float d0 = 0.f, d1 = 0.f, d2 = 0.f, d3 = 0.f;
    float a0 = 0.f, a1 = 0.f, a2 = 0.f, a3 = 0.f;

    for (int base = start; base < end; base += 64) {
        int nloc = end - base; if (nloc > 64) nloc = 64;
        if (t < nloc) {
            int src = csr_src[base + t];
            s_src[t] = src;
            float4 as = ((const float4*)a_s1)[src];
            float e0 = as.x + ad.x; e0 = e0 > 0.f ? e0 : NEG_SLOPE * e0;
            float e1 = as.y + ad.y; e1 = e1 > 0.f ? e1 : NEG_SLOPE * e1;
            float e2 = as.z + ad.z; e2 = e2 > 0.f ? e2 : NEG_SLOPE * e2;
            float e3 = as.w + ad.w; e3 = e3 > 0.f ? e3 : NEG_SLOPE * e3;
            float x0 = expf(e0), x1 = expf(e1), x2 = expf(e2), x3 = expf(e3);
            s_ex[t][0] = x0; s_ex[t][1] = x1; s_ex[t][2] = x2; s_ex[t][3] = x3;
            d0 += x0; d1 += x1; d2 += x2; d3 += x3;
        }
        __syncthreads();
        int j = 0;
        for (; j + 7 < nloc; j += 8) {
            uint2 v[8];
#pragma unroll
            for (int q = 0; q < 8; ++q)
                v[q] = ((const uint2*)(h1b + (size_t)s_src[j + q] * 256))[t];
#pragma unroll
            for (int q = 0; q < 8; ++q) {
                float e = s_ex[j + q][h];
                a0 += e * bflo(v[q].x); a1 += e * bfhi(v[q].x);
                a2 += e * bflo(v[q].y); a3 += e * bfhi(v[q].y);
            }
        }
        for (; j < nloc; ++j) {
            uint2 v = ((const uint2*)(h1b + (size_t)s_src[j] * 256))[t];
            float e = s_ex[j][h];
            a0 += e * bflo(v.x); a1 += e * bfhi(v.x);
            a2 += e * bflo(v.y); a3 += e * bfhi(v.y);
        }
        __syncthreads();
    }
#pragma unroll
    for (int o = 32; o > 0; o >>= 1) {
        d0 += __shfl_xor(d0, o); d1 += __shfl_xor(d1, o);
        d2 += __shfl_xor(d2, o); d3 += __shfl_xor(d3, o);
    }
    float den = (h == 0) ? d0 : (h == 1) ? d1 : (h == 2) ? d2 : d3;
    float inv = 1.0f / den;
    float4 bb = ((const float4*)b1)[t];
    float v0 = a0 * inv + bb.x; v0 = v0 > 0.f ? v0 : (expf(v0) - 1.f);
    float v1 = a1 * inv + bb.y; v1 = v1 > 0.f ? v1 : (expf(v1) - 1.f);
    float v2 = a2 * inv + bb.z; v2 = v2 > 0.f ? v2 : (expf(v2) - 1.f);
    float v3 = a3 * inv + bb.w; v3 = v3 > 0.f ? v3 : (expf(v3) - 1.f);
    __hip_bfloat162 p0, p1;
    p0.x = __float2bfloat16(v0); p0.y = __float2bfloat16(v1);
    p1.x = __float2bfloat16(v2); p1.y = __float2bfloat16(v3);
    __hip_bfloat162* op = (__hip_bfloat162*)(h2b + (size_t)dst * 256);
    op[2 * t] = p0; op[2 * t + 1] = p1;
}

// ============ Layer 2 GEMM: (N,256)x(256,64), 32 rows/block ============
__global__ __launch_bounds__(256) void k_gemm2_att(
    const __hip_bfloat16* __restrict__ h2b, const float* __restrict__ W2,
    const float* __restrict__ as2, const float* __restrict__ ad2,
    __hip_bfloat16* __restrict__ h3b, float* __restrict__ a_s2, float* __restrict__ a_d2,
    int N)
{
    const int n0 = blockIdx.x * 32, t = threadIdx.x;
    const int col = t & 63, rg = t >> 6;
    __shared__ float hs[32 * 256];        // 32 KB
    {
        const int nrows = (N - n0 < 32) ? (N - n0) : 32;
        const unsigned* hu = (const unsigned*)(h2b + (size_t)n0 * 256);
        const int tot = nrows * 128;      // dwords
        for (int i = t; i < tot; i += 256) {
            unsigned u = hu[i];
            hs[2 * i]     = bflo(u);
            hs[2 * i + 1] = bfhi(u);
        }
    }
    __syncthreads();
    float acc[8];
#pragma unroll
    for (int r = 0; r < 8; ++r) acc[r] = 0.f;
    const float4* hs4 = (const float4*)hs;   // hs4[row*64 + kb]
#pragma unroll 2
    for (int kb = 0; kb < 64; ++kb) {
        float w0 = W2[(4 * kb + 0) * 64 + col];
        float w1 = W2[(4 * kb + 1) * 64 + col];
        float w2 = W2[(4 * kb + 2) * 64 + col];
        float w3 = W2[(4 * kb + 3) * 64 + col];
#pragma unroll
        for (int r = 0; r < 8; ++r) {
            float4 hv = hs4[(rg * 8 + r) * 64 + kb];
            acc[r] += hv.x * w0 + hv.y * w1 + hv.z * w2 + hv.w * w3;
        }
    }
    float vas = as2[col], vad = ad2[col];
#pragma unroll
    for (int r = 0; r < 8; ++r) {
        int row = n0 + rg * 8 + r;
        if (row < N) h3b[(size_t)row * 64 + col] = __float2bfloat16(acc[r]);
        float s = acc[r] * vas, d = acc[r] * vad;
#pragma unroll
        for (int o = 32; o > 0; o >>= 1) { s += __shfl_down(s, o); d += __shfl_down(d, o); }
        if ((t & 63) == 0 && row < N) { a_s2[row] = s; a_d2[row] = d; }
    }
}

// ============ Layer 2 fused softmax+aggregate + b2 -> out ============
__global__ __launch_bounds__(64) void k_agg2_fused(const int* __restrict__ rowptr,
    const int* __restrict__ csr_src, const float* __restrict__ a_s2,
    const float* __restrict__ a_d2, const __hip_bfloat16* __restrict__ h3b,
    const float* __restrict__ b2, float* __restrict__ out, int N)
{
    const int t = threadIdx.x, half = t >> 5, l = t & 31;
    const int dst = blockIdx.x * 2 + half;
    const bool valid = dst < N;
    int start = 0, end = 0;
    float adv = 0.f;
    if (valid) { start = rowptr[dst]; end = rowptr[dst + 1]; adv = a_d2[dst]; }
    int trips = (end - start + 31) >> 5;
#pragma unroll
    for (int o = 32; o > 0; o >>= 1) { int u = __shfl_xor(trips, o); trips = u > trips ? u : trips; }
    __shared__ int   s_src[2][32];
    __shared__ float s_ex[2][32];
    float den = 0.f, acc0 = 0.f, acc1 = 0.f;

    for (int it = 0; it < trips; ++it) {
        int base = start + it * 32;
        int nloc = end - base; if (nloc > 32) nloc = 32; if (nloc < 0) nloc = 0;
        if (l < nloc) {
            int src = csr_src[base + l];
            s_src[half][l] = src;
            float e = a_s2[src] + adv;
            e = e > 0.f ? e : NEG_SLOPE * e;
            float ex = expf(e);
            s_ex[half][l] = ex;
            den += ex;
        }
        __syncthreads();
        int j = 0;
        for (; j + 7 < nloc; j += 8) {
            unsigned v[8];
#pragma unroll
            for (int q = 0; q < 8; ++q)
                v[q] = ((const unsigned*)(h3b + (size_t)s_src[half][j + q] * 64))[l];
#pragma unroll
            for (int q = 0; q < 8; ++q) {
                float e = s_ex[half][j + q];
                acc0 += e * bflo(v[q]); acc1 += e * bfhi(v[q]);
            }
        }
        for (; j < nloc; ++j) {
            unsigned v = ((const unsigned*)(h3b + (size_t)s_src[half][j] * 64))[l];
            float e = s_ex[half][j];
            acc0 += e * bflo(v); acc1 += e * bfhi(v);
        }
        __syncthreads();
    }
#pragma unroll
    for (int o = 16; o > 0; o >>= 1) den += __shfl_xor(den, o);
    if (valid) {
        float inv = 1.0f / den;
        float2 bb = ((const float2*)b2)[l];
        float2 ov; ov.x = acc0 * inv + bb.x; ov.y = acc1 * inv + bb.y;
        ((float2*)(out + (size_t)dst * 64))[l] = ov;
    }
}

extern "C" void kernel_launch(void* const* d_in, const int* in_sizes, int n_in,
                              void* d_out, int out_size, void* d_ws, size_t ws_size,
                              hipStream_t stream)
{
    const float* x   = (const float*)d_in[0];
    const int*   ei  = (const int*)d_in[1];
    const float* W1  = (const float*)d_in[2];
    const float* as1 = (const float*)d_in[3];
    const float* ad1 = (const float*)d_in[4];
    const float* b1  = (const float*)d_in[5];
    const float* W2  = (const float*)d_in[6];
    const float* as2 = (const float*)d_in[7];
    const float* ad2 = (const float*)d_in[8];
    const float* b2  = (const float*)d_in[9];
    float* out = (float*)d_out;

    const int N = in_sizes[0] / 128;      // 50000
    const int E = in_sizes[1] / 2;        // 800000
    const int M = E + N;                  // edges + self loops
    const int NB = (N + 255) / 256;       // scan blocks

    // ---- workspace layout (256B-aligned), ~63 MB ----
    char* w = (char*)d_ws;
    size_t o = 0;
    auto alloc = [&](size_t bytes) { size_t r = o; o = (o + bytes + 255) & ~(size_t)255; return r; };
    __hip_bfloat16* h1b   = (__hip_bfloat16*)(w + alloc((size_t)N * 256 * 2)); // 25.6 MB
    float* a_s1           = (float*)(w + alloc((size_t)N * 4 * 4));
    float* a_d1           = (float*)(w + alloc((size_t)N * 4 * 4));
    __hip_bfloat16* h2b   = (__hip_bfloat16*)(w + alloc((size_t)N * 256 * 2)); // 25.6 MB
    __hip_bfloat16* h3b   = (__hip_bfloat16*)(w + alloc((size_t)N * 64 * 2));  // 6.4 MB
    float* a_s2           = (float*)(w + alloc((size_t)N * 4));
    float* a_d2           = (float*)(w + alloc((size_t)N * 4));
    int* deg              = (int*)(w + alloc((size_t)N * 4));
    int* cnt              = (int*)(w + alloc((size_t)N * 4));
    int* rowptr           = (int*)(w + alloc((size_t)(N + 1) * 4));
    int* excl             = (int*)(w + alloc((size_t)N * 4));
    int* bsum             = (int*)(w + alloc((size_t)NB * 4));
    int* boff             = (int*)(w + alloc((size_t)NB * 4));
    int* csr_src          = (int*)(w + alloc((size_t)M * 4));                  // 3.4 MB
    __hip_bfloat16* W1t   = (__hip_bfloat16*)(w + alloc((size_t)256 * KP * 2));

    // ---- CSR build (shared by both layers) ----
    hipMemsetAsync(deg, 0, (size_t)N * 4, stream);
    hipMemsetAsync(cnt, 0, (size_t)N * 4, stream);
    k_hist<<<(M + 255) / 256, 256, 0, stream>>>(ei, E, M, deg);
    k_scan1<<<NB, 256, 0, stream>>>(deg, N, excl, bsum);
    k_scan2<<<1, 256, 0, stream>>>(bsum, NB, boff);
    k_scan3<<<NB, 256, 0, stream>>>(excl, boff, N, M, rowptr);
    k_scatter<<<(M + 255) / 256, 256, 0, stream>>>(ei, E, M, rowptr, cnt, csr_src);

    // ---- layer 1 ----
    k_prepW1<<<(256 * KP + 255) / 256, 256, 0, stream>>>(W1, W1t);
    k_gemm1_mfma<<<dim3((N + 63) / 64, 2), 256, 0, stream>>>(x, W1t, h1b, N);
    k_att1<<<(N + 3) / 4, 256, 0, stream>>>(h1b, as1, ad1, a_s1, a_d1, N);
    k_agg1_fused<<<N, 64, 0, stream>>>(rowptr, csr_src, a_s1, a_d1, h1b, b1, h2b);

    // ---- layer 2 ----
    k_gemm2_att<<<(N + 31) / 32, 256, 0, stream>>>(h2b, W2, as2, ad2, h3b, a_s2, a_d2, N);
    k_agg2_fused<<<(N + 1) / 2, 64, 0, stream>>>(rowptr, csr_src, a_s2, a_d2, h3b, b2, out, N);
}

// Round 8
// 304.298 us; speedup vs baseline: 1.5352x; 1.1388x over previous
//
#include <hip/hip_runtime.h>
#include <hip/hip_bf16.h>

#define NEG_SLOPE 0.2f

typedef __attribute__((ext_vector_type(8))) short short8;   // 8 bf16 (4 VGPRs)
typedef __attribute__((ext_vector_type(4))) float f32x4;    // MFMA accumulator

__device__ __forceinline__ float bflo(unsigned u) { return __uint_as_float(u << 16); }
__device__ __forceinline__ float bfhi(unsigned u) { return __uint_as_float(u & 0xffff0000u); }
__device__ __forceinline__ unsigned pk2bf(float a, float b) {
    __hip_bfloat162 t; t.x = __float2bfloat16(a); t.y = __float2bfloat16(b);
    return *reinterpret_cast<unsigned*>(&t);
}

#define KP  136   // padded k-stride for gemm1 tiles (128+8)
#define KP2 264   // padded k-stride for gemm2 tiles (256+8)

// ============ prep: W1 -> W1t bf16 [256][KP]; W2 -> W2t bf16 [64][KP2] ============
__global__ void k_prep(const float* __restrict__ W1, const float* __restrict__ W2,
    __hip_bfloat16* __restrict__ W1t, __hip_bfloat16* __restrict__ W2t)
{
    int i = blockIdx.x * 256 + threadIdx.x;
    if (i < 256 * KP) {
        int n = i / KP, k = i % KP;
        W1t[i] = __float2bfloat16(k < 128 ? W1[k * 256 + n] : 0.f);
    } else {
        int j = i - 256 * KP;
        if (j < 64 * KP2) {
            int n = j / KP2, k = j % KP2;
            W2t[j] = __float2bfloat16(k < 256 ? W2[k * 64 + n] : 0.f);
        }
    }
}

// ============ Layer 1 GEMM via MFMA + fused att dots ============
// Block: 64 rows x 128 cols (blockIdx.y = col half -> heads {2y, 2y+1}).
// 4 waves x 16-row strips. a_s1/a_d1 dots from fp32 acc, quad-local xor-reduce.
__global__ __launch_bounds__(256) void k_gemm1_mfma(
    const float* __restrict__ x, const __hip_bfloat16* __restrict__ W1t,
    const float* __restrict__ as1, const float* __restrict__ ad1,
    __hip_bfloat16* __restrict__ h1b, float* __restrict__ a_s1, float* __restrict__ a_d1,
    int N)
{
    const int n0 = blockIdx.x * 64;
    const int c0 = blockIdx.y * 128;
    const int t = threadIdx.x, wv = t >> 6, lane = t & 63;
    const int l15 = lane & 15, q = lane >> 4;

    __shared__ short sA[64 * KP];    // 17408 B
    __shared__ short sB[128 * KP];   // 34816 B

    {   // stage A: x fp32 -> bf16, stride KP
        const float4* x4 = (const float4*)x;
        for (int i = t; i < 2048; i += 256) {
            int row = i >> 5, kq = i & 31;
            float4 v = make_float4(0.f, 0.f, 0.f, 0.f);
            if (n0 + row < N) v = x4[(size_t)(n0 + row) * 32 + kq];
            uint2 p; p.x = pk2bf(v.x, v.y); p.y = pk2bf(v.z, v.w);
            *(uint2*)(sA + row * KP + kq * 4) = p;
        }
    }
    {   // stage B: contiguous copy of this col-half of W1t
        const uint4* src = (const uint4*)((const short*)W1t + (size_t)c0 * KP);
        uint4* dst = (uint4*)sB;
        for (int i = t; i < (128 * KP * 2) / 16; i += 256) dst[i] = src[i];
    }
    __syncthreads();

    short8 af[4];
#pragma unroll
    for (int kc = 0; kc < 4; ++kc)
        af[kc] = *(const short8*)(sA + (wv * 16 + l15) * KP + kc * 32 + q * 8);

    f32x4 acc[8];
#pragma unroll
    for (int nt = 0; nt < 8; ++nt) {
        f32x4 a = {0.f, 0.f, 0.f, 0.f};
#pragma unroll
        for (int kc = 0; kc < 4; ++kc) {
            short8 bf = *(const short8*)(sB + (nt * 16 + l15) * KP + kc * 32 + q * 8);
            a = __builtin_amdgcn_mfma_f32_16x16x32_bf16(af[kc], bf, a, 0, 0, 0);
        }
        acc[nt] = a;
    }

    // epilogue 1: store h1 (row=quad*4+reg, col=lane&15)
#pragma unroll
    for (int nt = 0; nt < 8; ++nt) {
#pragma unroll
        for (int r = 0; r < 4; ++r) {
            int row = n0 + wv * 16 + q * 4 + r;
            if (row < N)
                h1b[(size_t)row * 256 + c0 + nt * 16 + l15] = __float2bfloat16(acc[nt][r]);
        }
    }

    // epilogue 2: fused attention dots for heads {2y, 2y+1}
    float asv[8], adv[8];
#pragma unroll
    for (int nt = 0; nt < 8; ++nt) {
        asv[nt] = as1[c0 + nt * 16 + l15];
        adv[nt] = ad1[c0 + nt * 16 + l15];
    }
    const int hb = blockIdx.y * 2;
#pragma unroll
    for (int r = 0; r < 4; ++r) {
        float slo = 0.f, shi = 0.f, dlo = 0.f, dhi = 0.f;
#pragma unroll
        for (int nt = 0; nt < 4; ++nt) { slo += acc[nt][r] * asv[nt]; dlo += acc[nt][r] * adv[nt]; }
#pragma unroll
        for (int nt = 4; nt < 8; ++nt) { shi += acc[nt][r] * asv[nt]; dhi += acc[nt][r] * adv[nt]; }
#pragma unroll
        for (int o = 1; o < 16; o <<= 1) {
            slo += __shfl_xor(slo, o); shi += __shfl_xor(shi, o);
            dlo += __shfl_xor(dlo, o); dhi += __shfl_xor(dhi, o);
        }
        int row = n0 + wv * 16 + q * 4 + r;
        if (l15 == 0 && row < N) {
            a_s1[row * 4 + hb]     = slo; a_s1[row * 4 + hb + 1] = shi;
            a_d1[row * 4 + hb]     = dlo; a_d1[row * 4 + hb + 1] = dhi;
        }
    }
}

// ============ CSR build ============
__global__ void k_hist(const int* __restrict__ ei, int E, int M, int* __restrict__ deg)
{
    int i = blockIdx.x * blockDim.x + threadIdx.x;
    if (i >= M) return;
    int dst = (i < E) ? ei[E + i] : (i - E);
    atomicAdd(&deg[dst], 1);
}

__global__ __launch_bounds__(256) void k_scan1(const int* __restrict__ deg, int N,
    int* __restrict__ excl, int* __restrict__ bsum)
{
    __shared__ int s[256];
    int t = threadIdx.x, i = blockIdx.x * 256 + t;
    int v = (i < N) ? deg[i] : 0;
    s[t] = v; __syncthreads();
#pragma unroll
    for (int o = 1; o < 256; o <<= 1) {
        int x = (t >= o) ? s[t - o] : 0;
        __syncthreads();
        s[t] += x;
        __syncthreads();
    }
    if (i < N) excl[i] = s[t] - v;
    if (t == 255) bsum[blockIdx.x] = s[255];
}

__global__ __launch_bounds__(256) void k_scan2(const int* __restrict__ bsum, int NB,
    int* __restrict__ boff)
{
    __shared__ int s[256];
    int t = threadIdx.x;
    int v = (t < NB) ? bsum[t] : 0;
    s[t] = v; __syncthreads();
#pragma unroll
    for (int o = 1; o < 256; o <<= 1) {
        int x = (t >= o) ? s[t - o] : 0;
        __syncthreads();
        s[t] += x;
        __syncthreads();
    }
    if (t < NB) boff[t] = s[t] - v;
}

__global__ void k_scan3(const int* __restrict__ excl, const int* __restrict__ boff,
    int N, int M, int* __restrict__ rowptr)
{
    int i = blockIdx.x * blockDim.x + threadIdx.x;
    if (i < N) rowptr[i] = excl[i] + boff[i >> 8];
    if (i == 0) rowptr[N] = M;
}

__global__ void k_scatter(const int* __restrict__ ei, int E, int M,
    const int* __restrict__ rowptr, int* __restrict__ cnt, int* __restrict__ csr_src)
{
    int i = blockIdx.x * blockDim.x + threadIdx.x;
    if (i >= M) return;
    int src, dst;
    if (i < E) { src = ei[i]; dst = ei[E + i]; } else { src = i - E; dst = src; }
    int pos = rowptr[dst] + atomicAdd(&cnt[dst], 1);
    csr_src[pos] = src;
}

// ============ Layer 1 fused softmax+aggregate+bias+ELU ============
// Single wave per dst -> wave64 lockstep, no barriers needed (LDS ops in-order).
__global__ __launch_bounds__(64) void k_agg1_fused(const int* __restrict__ rowptr,
    const int* __restrict__ csr_src, const float* __restrict__ a_s1,
    const float* __restrict__ a_d1, const __hip_bfloat16* __restrict__ h1b,
    const float* __restrict__ b1, __hip_bfloat16* __restrict__ h2b)
{
    const int dst = blockIdx.x, t = threadIdx.x;
    const int h = t >> 4;
    const int start = rowptr[dst], end = rowptr[dst + 1];
    __shared__ int   s_src[64];
    __shared__ float s_ex[64][4];
    float4 ad = ((const float4*)a_d1)[dst];
    float d0 = 0.f, d1 = 0.f, d2 = 0.f, d3 = 0.f;
    float a0 = 0.f, a1 = 0.f, a2 = 0.f, a3 = 0.f;

    for (int base = start; base < end; base += 64) {
        int nloc = end - base; if (nloc > 64) nloc = 64;
        if (t < nloc) {
            int src = csr_src[base + t];
            s_src[t] = src;
            float4 as = ((const float4*)a_s1)[src];
            float e0 = as.x + ad.x; e0 = e0 > 0.f ? e0 : NEG_SLOPE * e0;
            float e1 = as.y + ad.y; e1 = e1 > 0.f ? e1 : NEG_SLOPE * e1;
            float e2 = as.z + ad.z; e2 = e2 > 0.f ? e2 : NEG_SLOPE * e2;
            float e3 = as.w + ad.w; e3 = e3 > 0.f ? e3 : NEG_SLOPE * e3;
            float x0 = expf(e0), x1 = expf(e1), x2 = expf(e2), x3 = expf(e3);
            s_ex[t][0] = x0; s_ex[t][1] = x1; s_ex[t][2] = x2; s_ex[t][3] = x3;
            d0 += x0; d1 += x1; d2 += x2; d3 += x3;
        }
        int j = 0;
        for (; j + 7 < nloc; j += 8) {
            uint2 v[8];
#pragma unroll
            for (int q = 0; q < 8; ++q)
                v[q] = ((const uint2*)(h1b + (size_t)s_src[j + q] * 256))[t];
#pragma unroll
            for (int q = 0; q < 8; ++q) {
                float e = s_ex[j + q][h];
                a0 += e * bflo(v[q].x); a1 += e * bfhi(v[q].x);
                a2 += e * bflo(v[q].y); a3 += e * bfhi(v[q].y);
            }
        }
        for (; j < nloc; ++j) {
            uint2 v = ((const uint2*)(h1b + (size_t)s_src[j] * 256))[t];
            float e = s_ex[j][h];
            a0 += e * bflo(v.x); a1 += e * bfhi(v.x);
            a2 += e * bflo(v.y); a3 += e * bfhi(v.y);
        }
    }
#pragma unroll
    for (int o = 32; o > 0; o >>= 1) {
        d0 += __shfl_xor(d0, o); d1 += __shfl_xor(d1, o);
        d2 += __shfl_xor(d2, o); d3 += __shfl_xor(d3, o);
    }
    float den = (h == 0) ? d0 : (h == 1) ? d1 : (h == 2) ? d2 : d3;
    float inv = 1.0f / den;
    float4 bb = ((const float4*)b1)[t];
    float v0 = a0 * inv + bb.x; v0 = v0 > 0.f ? v0 : (expf(v0) - 1.f);
    float v1 = a1 * inv + bb.y; v1 = v1 > 0.f ? v1 : (expf(v1) - 1.f);
    float v2 = a2 * inv + bb.z; v2 = v2 > 0.f ? v2 : (expf(v2) - 1.f);
    float v3 = a3 * inv + bb.w; v3 = v3 > 0.f ? v3 : (expf(v3) - 1.f);
    __hip_bfloat162 p0, p1;
    p0.x = __float2bfloat16(v0); p0.y = __float2bfloat16(v1);
    p1.x = __float2bfloat16(v2); p1.y = __float2bfloat16(v3);
    __hip_bfloat162* op = (__hip_bfloat162*)(h2b + (size_t)dst * 256);
    op[2 * t] = p0; op[2 * t + 1] = p1;
}

// ============ Layer 2 GEMM via MFMA + fused att dots ============
// Block: 32 rows x 64 cols. 4 waves: wv&1 = 16-row strip, wv>>1 = 32-col half.
// att dots: quad-local xor-reduce then atomicAdd (a_s2/a_d2 pre-zeroed).
__global__ __launch_bounds__(256) void k_gemm2_mfma(
    const __hip_bfloat16* __restrict__ h2b, const __hip_bfloat16* __restrict__ W2t,
    const float* __restrict__ as2, const float* __restrict__ ad2,
    __hip_bfloat16* __restrict__ h3b, float* __restrict__ a_s2, float* __restrict__ a_d2,
    int N)
{
    const int n0 = blockIdx.x * 32;
    const int t = threadIdx.x, wv = t >> 6, lane = t & 63;
    const int l15 = lane & 15, q = lane >> 4;
    const int rs = wv & 1, ch = wv >> 1;

    __shared__ short sA[32 * KP2];   // 16896 B
    __shared__ short sB[64 * KP2];   // 33792 B

    {   // stage B: full W2t (already padded KP2) — straight copy
        const uint4* src = (const uint4*)W2t;
        uint4* dst = (uint4*)sB;
        for (int i = t; i < (64 * KP2 * 2) / 16; i += 256) dst[i] = src[i];
    }
    {   // stage A: 32 h2 rows (bf16, contiguous 512 B each) -> stride KP2
        for (int i = t; i < 1024; i += 256) {
            int row = i >> 5, kq = i & 31;
            uint4 v = make_uint4(0, 0, 0, 0);
            if (n0 + row < N) v = ((const uint4*)(h2b + (size_t)(n0 + row) * 256))[kq];
            *(uint4*)(sA + row * KP2 + kq * 8) = v;
        }
    }
    __syncthreads();

    short8 af[8];
#pragma unroll
    for (int kc = 0; kc < 8; ++kc)
        af[kc] = *(const short8*)(sA + (rs * 16 + l15) * KP2 + kc * 32 + q * 8);

    f32x4 acc[2];
#pragma unroll
    for (int nt = 0; nt < 2; ++nt) {
        f32x4 a = {0.f, 0.f, 0.f, 0.f};
#pragma unroll
        for (int kc = 0; kc < 8; ++kc) {
            short8 bf = *(const short8*)(sB + (ch * 32 + nt * 16 + l15) * KP2 + kc * 32 + q * 8);
            a = __builtin_amdgcn_mfma_f32_16x16x32_bf16(af[kc], bf, a, 0, 0, 0);
        }
        acc[nt] = a;
    }

    float asv[2], adv[2];
#pragma unroll
    for (int nt = 0; nt < 2; ++nt) {
        int col = ch * 32 + nt * 16 + l15;
        asv[nt] = as2[col]; adv[nt] = ad2[col];
    }
#pragma unroll
    for (int r = 0; r < 4; ++r) {
        int row = n0 + rs * 16 + q * 4 + r;
        if (row < N) {
#pragma unroll
            for (int nt = 0; nt < 2; ++nt)
                h3b[(size_t)row * 64 + ch * 32 + nt * 16 + l15] = __float2bfloat16(acc[nt][r]);
        }
        float s = acc[0][r] * asv[0] + acc[1][r] * asv[1];
        float d = acc[0][r] * adv[0] + acc[1][r] * adv[1];
#pragma unroll
        for (int o = 1; o < 16; o <<= 1) { s += __shfl_xor(s, o); d += __shfl_xor(d, o); }
        if (l15 == 0 && row < N) {
            atomicAdd(&a_s2[row], s);
            atomicAdd(&a_d2[row], d);
        }
    }
}

// ============ Layer 2 fused softmax+aggregate + b2 -> out ============
// Single wave, two dsts (32-lane halves) -> lockstep, no barriers.
__global__ __launch_bounds__(64) void k_agg2_fused(const int* __restrict__ rowptr,
    const int* __restrict__ csr_src, const float* __restrict__ a_s2,
    const float* __restrict__ a_d2, const __hip_bfloat16* __restrict__ h3b,
    const float* __restrict__ b2, float* __restrict__ out, int N)
{
    const int t = threadIdx.x, half = t >> 5, l = t & 31;
    const int dst = blockIdx.x * 2 + half;
    const bool valid = dst < N;
    int start = 0, end = 0;
    float adv = 0.f;
    if (valid) { start = rowptr[dst]; end = rowptr[dst + 1]; adv = a_d2[dst]; }
    int trips = (end - start + 31) >> 5;
#pragma unroll
    for (int o = 32; o > 0; o >>= 1) { int u = __shfl_xor(trips, o); trips = u > trips ? u : trips; }
    __shared__ int   s_src[2][32];
    __shared__ float s_ex[2][32];
    float den = 0.f, acc0 = 0.f, acc1 = 0.f;

    for (int it = 0; it < trips; ++it) {
        int base = start + it * 32;
        int nloc = end - base; if (nloc > 32) nloc = 32; if (nloc < 0) nloc = 0;
        if (l < nloc) {
            int src = csr_src[base + l];
            s_src[half][l] = src;
            float e = a_s2[src] + adv;
            e = e > 0.f ? e : NEG_SLOPE * e;
            float ex = expf(e);
            s_ex[half][l] = ex;
            den += ex;
        }
        int j = 0;
        for (; j + 7 < nloc; j += 8) {
            unsigned v[8];
#pragma unroll
            for (int q = 0; q < 8; ++q)
                v[q] = ((const unsigned*)(h3b + (size_t)s_src[half][j + q] * 64))[l];
#pragma unroll
            for (int q = 0; q < 8; ++q) {
                float e = s_ex[half][j + q];
                acc0 += e * bflo(v[q]); acc1 += e * bfhi(v[q]);
            }
        }
        for (; j < nloc; ++j) {
            unsigned v = ((const unsigned*)(h3b + (size_t)s_src[half][j] * 64))[l];
            float e = s_ex[half][j];
            acc0 += e * bflo(v); acc1 += e * bfhi(v);
        }
    }
#pragma unroll
    for (int o = 16; o > 0; o >>= 1) den += __shfl_xor(den, o);
    if (valid) {
        float inv = 1.0f / den;
        float2 bb = ((const float2*)b2)[l];
        float2 ov; ov.x = acc0 * inv + bb.x; ov.y = acc1 * inv + bb.y;
        ((float2*)(out + (size_t)dst * 64))[l] = ov;
    }
}

extern "C" void kernel_launch(void* const* d_in, const int* in_sizes, int n_in,
                              void* d_out, int out_size, void* d_ws, size_t ws_size,
                              hipStream_t stream)
{
    const float* x   = (const float*)d_in[0];
    const int*   ei  = (const int*)d_in[1];
    const float* W1  = (const float*)d_in[2];
    const float* as1 = (const float*)d_in[3];
    const float* ad1 = (const float*)d_in[4];
    const float* b1  = (const float*)d_in[5];
    const float* W2  = (const float*)d_in[6];
    const float* as2 = (const float*)d_in[7];
    const float* ad2 = (const float*)d_in[8];
    const float* b2  = (const float*)d_in[9];
    float* out = (float*)d_out;

    const int N = in_sizes[0] / 128;      // 50000
    const int E = in_sizes[1] / 2;        // 800000
    const int M = E + N;                  // edges + self loops
    const int NB = (N + 255) / 256;       // scan blocks

    // ---- workspace layout (256B-aligned) ----
    char* w = (char*)d_ws;
    size_t o = 0;
    auto alloc = [&](size_t bytes) { size_t r = o; o = (o + bytes + 255) & ~(size_t)255; return r; };
    __hip_bfloat16* h1b   = (__hip_bfloat16*)(w + alloc((size_t)N * 256 * 2)); // 25.6 MB
    float* a_s1           = (float*)(w + alloc((size_t)N * 4 * 4));
    float* a_d1           = (float*)(w + alloc((size_t)N * 4 * 4));
    __hip_bfloat16* h2b   = (__hip_bfloat16*)(w + alloc((size_t)N * 256 * 2)); // 25.6 MB
    __hip_bfloat16* h3b   = (__hip_bfloat16*)(w + alloc((size_t)N * 64 * 2));  // 6.4 MB
    // zero-block: a_s2 | a_d2 | deg | cnt — one memset covers the span
    size_t z0 = o;
    float* a_s2           = (float*)(w + alloc((size_t)N * 4));
    float* a_d2           = (float*)(w + alloc((size_t)N * 4));
    int* deg              = (int*)(w + alloc((size_t)N * 4));
    int* cnt              = (int*)(w + alloc((size_t)N * 4));
    size_t z1 = o;
    int* rowptr           = (int*)(w + alloc((size_t)(N + 1) * 4));
    int* excl             = (int*)(w + alloc((size_t)N * 4));
    int* bsum             = (int*)(w + alloc((size_t)NB * 4));
    int* boff             = (int*)(w + alloc((size_t)NB * 4));
    int* csr_src          = (int*)(w + alloc((size_t)M * 4));                  // 3.4 MB
    __hip_bfloat16* W1t   = (__hip_bfloat16*)(w + alloc((size_t)256 * KP * 2));
    __hip_bfloat16* W2t   = (__hip_bfloat16*)(w + alloc((size_t)64 * KP2 * 2));

    // ---- zero + prep ----
    hipMemsetAsync(w + z0, 0, z1 - z0, stream);
    const int prepTot = 256 * KP + 64 * KP2;
    k_prep<<<(prepTot + 255) / 256, 256, 0, stream>>>(W1, W2, W1t, W2t);

    // ---- CSR build ----
    k_hist<<<(M + 255) / 256, 256, 0, stream>>>(ei, E, M, deg);
    k_scan1<<<NB, 256, 0, stream>>>(deg, N, excl, bsum);
    k_scan2<<<1, 256, 0, stream>>>(bsum, NB, boff);
    k_scan3<<<NB, 256, 0, stream>>>(excl, boff, N, M, rowptr);
    k_scatter<<<(M + 255) / 256, 256, 0, stream>>>(ei, E, M, rowptr, cnt, csr_src);

    // ---- layer 1 ----
    k_gemm1_mfma<<<dim3((N + 63) / 64, 2), 256, 0, stream>>>(x, W1t, as1, ad1, h1b, a_s1, a_d1, N);
    k_agg1_fused<<<N, 64, 0, stream>>>(rowptr, csr_src, a_s1, a_d1, h1b, b1, h2b);

    // ---- layer 2 ----
    k_gemm2_mfma<<<(N + 31) / 32, 256, 0, stream>>>(h2b, W2t, as2, ad2, h3b, a_s2, a_d2, N);
    k_agg2_fused<<<(N + 1) / 2, 64, 0, stream>>>(rowptr, csr_src, a_s2, a_d2, h3b, b2, out, N);
}